// Round 2
// baseline (1669.558 us; speedup 1.0000x reference)
//
#include <hip/hip_runtime.h>

#define HID 128

// ---------------------------------------------------------------------------
// Detect whether edge_index was materialized as int64 (odd 32-bit words all 0)
// or int32. Values are node ids in [0, 50000) so the high word of int64 is 0.
// For int32 data the "odd words" are 128 random node ids — P(all zero) ~ 0.
// ---------------------------------------------------------------------------
__global__ void detect_idx64(const int* __restrict__ E, int* __restrict__ flag) {
    int l = threadIdx.x;                       // 64 threads
    int v = E[2 * l + 1] | E[2 * (l + 64) + 1];
    unsigned long long b = __ballot(v != 0);
    if (l == 0) flag[0] = (b == 0ull) ? 1 : 0;
}

__device__ __forceinline__ int load_idx(const int* __restrict__ E, int pos, bool is64) {
    return is64 ? E[2 * pos] : E[pos];
}

// ---------------------------------------------------------------------------
// Per-node MLP transform: T[n] = relu(X[n] @ W + B)   (W is 128x128, in LDS)
// mode 0: write T[n][0..127]
// mode 1: additionally dot with Wf (128x1) and write only S[n] (scalar)
// Layout: block = 256 threads = 4 waves; each 32-lane half-wave handles 2
// nodes; lane holds 4 columns (j0 = 4*l32). x broadcast via __shfl within the
// 32-group. W row slices read as ds_read_b128, conflict-free.
// ---------------------------------------------------------------------------
__global__ __launch_bounds__(256, 2) void mlp_layer(
    const float* __restrict__ X, const float* __restrict__ W,
    const float* __restrict__ Bv, const float* __restrict__ Wf,
    float* __restrict__ T, float* __restrict__ S, int n, int mode)
{
    __shared__ float Ws[HID * HID];            // 64 KiB
    {
        const float4* W4 = (const float4*)W;
        float4* d4 = (float4*)Ws;
        for (int i = threadIdx.x; i < (HID * HID / 4); i += 256) d4[i] = W4[i];
    }
    __syncthreads();

    const int wave = threadIdx.x >> 6;
    const int half = (threadIdx.x >> 5) & 1;
    const int l32  = threadIdx.x & 31;
    const int j0   = l32 * 4;

    for (int base = blockIdx.x * 16; base < n; base += gridDim.x * 16) {
        const int n0 = base + wave * 4 + half * 2;
        const int n1 = n0 + 1;
        float4 xv0 = {0.f, 0.f, 0.f, 0.f}, xv1 = {0.f, 0.f, 0.f, 0.f};
        if (n0 < n) xv0 = *(const float4*)(X + (size_t)n0 * HID + j0);
        if (n1 < n) xv1 = *(const float4*)(X + (size_t)n1 * HID + j0);

        float4 acc0 = {0.f, 0.f, 0.f, 0.f}, acc1 = {0.f, 0.f, 0.f, 0.f};
#pragma unroll
        for (int k4 = 0; k4 < 32; ++k4) {
            float x0b[4], x1b[4];
            x0b[0] = __shfl(xv0.x, k4, 32);
            x0b[1] = __shfl(xv0.y, k4, 32);
            x0b[2] = __shfl(xv0.z, k4, 32);
            x0b[3] = __shfl(xv0.w, k4, 32);
            x1b[0] = __shfl(xv1.x, k4, 32);
            x1b[1] = __shfl(xv1.y, k4, 32);
            x1b[2] = __shfl(xv1.z, k4, 32);
            x1b[3] = __shfl(xv1.w, k4, 32);
#pragma unroll
            for (int r = 0; r < 4; ++r) {
                const float4 w = *(const float4*)(Ws + (k4 * 4 + r) * HID + j0);
                acc0.x = fmaf(x0b[r], w.x, acc0.x);
                acc0.y = fmaf(x0b[r], w.y, acc0.y);
                acc0.z = fmaf(x0b[r], w.z, acc0.z);
                acc0.w = fmaf(x0b[r], w.w, acc0.w);
                acc1.x = fmaf(x1b[r], w.x, acc1.x);
                acc1.y = fmaf(x1b[r], w.y, acc1.y);
                acc1.z = fmaf(x1b[r], w.z, acc1.z);
                acc1.w = fmaf(x1b[r], w.w, acc1.w);
            }
        }

        const float4 bv = *(const float4*)(Bv + j0);
        acc0.x = fmaxf(acc0.x + bv.x, 0.f);
        acc0.y = fmaxf(acc0.y + bv.y, 0.f);
        acc0.z = fmaxf(acc0.z + bv.z, 0.f);
        acc0.w = fmaxf(acc0.w + bv.w, 0.f);
        acc1.x = fmaxf(acc1.x + bv.x, 0.f);
        acc1.y = fmaxf(acc1.y + bv.y, 0.f);
        acc1.z = fmaxf(acc1.z + bv.z, 0.f);
        acc1.w = fmaxf(acc1.w + bv.w, 0.f);

        if (mode == 0) {
            if (n0 < n) *(float4*)(T + (size_t)n0 * HID + j0) = acc0;
            if (n1 < n) *(float4*)(T + (size_t)n1 * HID + j0) = acc1;
        } else {
            const float4 wf = *(const float4*)(Wf + j0);
            float p0 = acc0.x * wf.x + acc0.y * wf.y + acc0.z * wf.z + acc0.w * wf.w;
            float p1 = acc1.x * wf.x + acc1.y * wf.y + acc1.z * wf.z + acc1.w * wf.w;
#pragma unroll
            for (int m = 16; m >= 1; m >>= 1) {
                p0 += __shfl_xor(p0, m);
                p1 += __shfl_xor(p1, m);
            }
            if (l32 == 0) {
                if (n0 < n) S[n0] = p0;
                if (n1 < n) S[n1] = p1;
            }
        }
    }
}

// ---------------------------------------------------------------------------
// Vector scatter: H[dst] += T[src] (128 floats per edge). 32 lanes per edge,
// 4 floats per lane, HW fp32 atomics.
// ---------------------------------------------------------------------------
__global__ __launch_bounds__(256) void scatter_vec(
    const float* __restrict__ T, const int* __restrict__ E,
    const int* __restrict__ flag, float* __restrict__ H,
    int n_edges, int n_nodes)
{
    const bool is64 = (flag[0] != 0);
    const int l32 = threadIdx.x & 31;
    const int j0  = l32 * 4;
    const int grp  = (int)((blockIdx.x * blockDim.x + threadIdx.x) >> 5);
    const int ngrp = (int)((gridDim.x * blockDim.x) >> 5);
    for (int e = grp; e < n_edges; e += ngrp) {
        const int src = load_idx(E, e, is64);
        const int dst = load_idx(E, n_edges + e, is64);
        if ((unsigned)src >= (unsigned)n_nodes || (unsigned)dst >= (unsigned)n_nodes) continue;
        const float4 v = *(const float4*)(T + (size_t)src * HID + j0);
        float* hp = H + (size_t)dst * HID + j0;
        unsafeAtomicAdd(hp + 0, v.x);
        unsafeAtomicAdd(hp + 1, v.y);
        unsafeAtomicAdd(hp + 2, v.z);
        unsafeAtomicAdd(hp + 3, v.w);
    }
}

// ---------------------------------------------------------------------------
// Scalar scatter for the fused layer-2 + readout: O[dst] += S[src]
// ---------------------------------------------------------------------------
__global__ __launch_bounds__(256) void scatter_scalar(
    const float* __restrict__ S, const int* __restrict__ E,
    const int* __restrict__ flag, float* __restrict__ O,
    int n_edges, int n_nodes)
{
    const bool is64 = (flag[0] != 0);
    const int t  = blockIdx.x * blockDim.x + threadIdx.x;
    const int nt = gridDim.x * blockDim.x;
    for (int e = t; e < n_edges; e += nt) {
        const int src = load_idx(E, e, is64);
        const int dst = load_idx(E, n_edges + e, is64);
        if ((unsigned)src >= (unsigned)n_nodes || (unsigned)dst >= (unsigned)n_nodes) continue;
        unsafeAtomicAdd(O + dst, S[src]);
    }
}

__global__ void init_out(float* __restrict__ O, const float* __restrict__ bf, int n) {
    int i = blockIdx.x * blockDim.x + threadIdx.x;
    if (i < n) O[i] = bf[0];
}

extern "C" void kernel_launch(void* const* d_in, const int* in_sizes, int n_in,
                              void* d_out, int out_size, void* d_ws, size_t ws_size,
                              hipStream_t stream) {
    const float* x  = (const float*)d_in[0];
    const int*   E  = (const int*)d_in[1];
    const float* W1 = (const float*)d_in[2];
    const float* b1 = (const float*)d_in[3];
    const float* W2 = (const float*)d_in[4];
    const float* b2 = (const float*)d_in[5];
    const float* Wf = (const float*)d_in[6];
    const float* bf = (const float*)d_in[7];
    float* out = (float*)d_out;

    const int n  = in_sizes[0] / HID;   // 50000 nodes
    const int ne = in_sizes[1] / 2;     // 800000 edges

    char* ws = (char*)d_ws;
    int*   flag = (int*)ws;
    float* t1   = (float*)(ws + 1024);                               // n*128 f32
    float* h1   = (float*)(ws + 1024 + (size_t)n * HID * 4);         // n*128 f32
    float* s    = t1;  // t1 is dead after scatter_vec; reuse for scalars

    detect_idx64<<<1, 64, 0, stream>>>(E, flag);

    // layer 1: per-node transform, then vector scatter
    mlp_layer<<<512, 256, 0, stream>>>(x, W1, b1, nullptr, t1, nullptr, n, 0);
    (void)hipMemsetAsync(h1, 0, (size_t)n * HID * 4, stream);
    scatter_vec<<<8192, 256, 0, stream>>>(t1, E, flag, h1, ne, n);

    // layer 2 fused with readout: s[m] = relu(h1[m]@W2+b2) . Wf
    mlp_layer<<<512, 256, 0, stream>>>(h1, W2, b2, Wf, nullptr, s, n, 1);

    // out[n] = bf + sum_{e: dst==n} s[src_e]
    init_out<<<(n + 255) / 256, 256, 0, stream>>>(out, bf, n);
    scatter_scalar<<<2048, 256, 0, stream>>>(s, E, flag, out, ne, n);
}

// Round 3
// 544.356 us; speedup vs baseline: 3.0670x; 3.0670x over previous
//
#include <hip/hip_runtime.h>

#define HID 128
#define SCAN_THREADS 1024

// ---------------------------------------------------------------------------
// Detect whether edge_index was materialized as int64 (odd 32-bit words all 0)
// or int32. Values are node ids in [0, 50000) so the high word of int64 is 0.
// ---------------------------------------------------------------------------
__global__ void detect_idx64(const int* __restrict__ E, int* __restrict__ flag) {
    int l = threadIdx.x;                       // 64 threads
    int v = E[2 * l + 1] | E[2 * (l + 64) + 1];
    unsigned long long b = __ballot(v != 0);
    if (l == 0) flag[0] = (b == 0ull) ? 1 : 0;
}

__device__ __forceinline__ int load_idx(const int* __restrict__ E, int pos, bool is64) {
    return is64 ? E[2 * pos] : E[pos];
}

// ---------------------------------------------------------------------------
// Per-node MLP transform: T[n] = relu(X[n] @ W + B)   (W is 128x128, in LDS)
// mode 0: write T[n][0..127]
// mode 1: additionally dot with Wf (128x1) and write only S[n] (scalar)
// ---------------------------------------------------------------------------
__global__ __launch_bounds__(256, 2) void mlp_layer(
    const float* __restrict__ X, const float* __restrict__ W,
    const float* __restrict__ Bv, const float* __restrict__ Wf,
    float* __restrict__ T, float* __restrict__ S, int n, int mode)
{
    __shared__ float Ws[HID * HID];            // 64 KiB
    {
        const float4* W4 = (const float4*)W;
        float4* d4 = (float4*)Ws;
        for (int i = threadIdx.x; i < (HID * HID / 4); i += 256) d4[i] = W4[i];
    }
    __syncthreads();

    const int wave = threadIdx.x >> 6;
    const int half = (threadIdx.x >> 5) & 1;
    const int l32  = threadIdx.x & 31;
    const int j0   = l32 * 4;

    for (int base = blockIdx.x * 16; base < n; base += gridDim.x * 16) {
        const int n0 = base + wave * 4 + half * 2;
        const int n1 = n0 + 1;
        float4 xv0 = {0.f, 0.f, 0.f, 0.f}, xv1 = {0.f, 0.f, 0.f, 0.f};
        if (n0 < n) xv0 = *(const float4*)(X + (size_t)n0 * HID + j0);
        if (n1 < n) xv1 = *(const float4*)(X + (size_t)n1 * HID + j0);

        float4 acc0 = {0.f, 0.f, 0.f, 0.f}, acc1 = {0.f, 0.f, 0.f, 0.f};
#pragma unroll
        for (int k4 = 0; k4 < 32; ++k4) {
            float x0b[4], x1b[4];
            x0b[0] = __shfl(xv0.x, k4, 32);
            x0b[1] = __shfl(xv0.y, k4, 32);
            x0b[2] = __shfl(xv0.z, k4, 32);
            x0b[3] = __shfl(xv0.w, k4, 32);
            x1b[0] = __shfl(xv1.x, k4, 32);
            x1b[1] = __shfl(xv1.y, k4, 32);
            x1b[2] = __shfl(xv1.z, k4, 32);
            x1b[3] = __shfl(xv1.w, k4, 32);
#pragma unroll
            for (int r = 0; r < 4; ++r) {
                const float4 w = *(const float4*)(Ws + (k4 * 4 + r) * HID + j0);
                acc0.x = fmaf(x0b[r], w.x, acc0.x);
                acc0.y = fmaf(x0b[r], w.y, acc0.y);
                acc0.z = fmaf(x0b[r], w.z, acc0.z);
                acc0.w = fmaf(x0b[r], w.w, acc0.w);
                acc1.x = fmaf(x1b[r], w.x, acc1.x);
                acc1.y = fmaf(x1b[r], w.y, acc1.y);
                acc1.z = fmaf(x1b[r], w.z, acc1.z);
                acc1.w = fmaf(x1b[r], w.w, acc1.w);
            }
        }

        const float4 bv = *(const float4*)(Bv + j0);
        acc0.x = fmaxf(acc0.x + bv.x, 0.f);
        acc0.y = fmaxf(acc0.y + bv.y, 0.f);
        acc0.z = fmaxf(acc0.z + bv.z, 0.f);
        acc0.w = fmaxf(acc0.w + bv.w, 0.f);
        acc1.x = fmaxf(acc1.x + bv.x, 0.f);
        acc1.y = fmaxf(acc1.y + bv.y, 0.f);
        acc1.z = fmaxf(acc1.z + bv.z, 0.f);
        acc1.w = fmaxf(acc1.w + bv.w, 0.f);

        if (mode == 0) {
            if (n0 < n) *(float4*)(T + (size_t)n0 * HID + j0) = acc0;
            if (n1 < n) *(float4*)(T + (size_t)n1 * HID + j0) = acc1;
        } else {
            const float4 wf = *(const float4*)(Wf + j0);
            float p0 = acc0.x * wf.x + acc0.y * wf.y + acc0.z * wf.z + acc0.w * wf.w;
            float p1 = acc1.x * wf.x + acc1.y * wf.y + acc1.z * wf.z + acc1.w * wf.w;
#pragma unroll
            for (int m = 16; m >= 1; m >>= 1) {
                p0 += __shfl_xor(p0, m);
                p1 += __shfl_xor(p1, m);
            }
            if (l32 == 0) {
                if (n0 < n) S[n0] = p0;
                if (n1 < n) S[n1] = p1;
            }
        }
    }
}

// ---------------------------------------------------------------------------
// CSR build: histogram of dst, block scan, permute src ids into dst order.
// ---------------------------------------------------------------------------
__global__ __launch_bounds__(256) void hist_dst(
    const int* __restrict__ E, const int* __restrict__ flag,
    int* __restrict__ cnt, int n_edges, int n_nodes)
{
    const bool is64 = (flag[0] != 0);
    const int t  = blockIdx.x * blockDim.x + threadIdx.x;
    const int nt = gridDim.x * blockDim.x;
    for (int e = t; e < n_edges; e += nt) {
        const int dst = load_idx(E, n_edges + e, is64);
        if ((unsigned)dst < (unsigned)n_nodes) atomicAdd(&cnt[dst], 1);
    }
}

__global__ __launch_bounds__(SCAN_THREADS) void scan_offsets(
    const int* __restrict__ cnt, int* __restrict__ offs, int* __restrict__ pos, int n)
{
    __shared__ int sums[SCAN_THREADS];
    const int t = threadIdx.x;
    const int chunk = (n + SCAN_THREADS - 1) / SCAN_THREADS;
    const int lo = t * chunk;
    const int hi = min(lo + chunk, n);
    int s = 0;
    for (int i = lo; i < hi; ++i) s += cnt[i];
    sums[t] = s;
    __syncthreads();
    for (int d = 1; d < SCAN_THREADS; d <<= 1) {
        int v = (t >= d) ? sums[t - d] : 0;
        __syncthreads();
        sums[t] += v;
        __syncthreads();
    }
    int run = (t > 0) ? sums[t - 1] : 0;   // exclusive prefix of this chunk
    for (int i = lo; i < hi; ++i) {
        offs[i] = run;
        pos[i]  = run;
        run += cnt[i];
    }
    if (t == SCAN_THREADS - 1) offs[n] = run;
}

__global__ __launch_bounds__(256) void build_perm(
    const int* __restrict__ E, const int* __restrict__ flag,
    int* __restrict__ pos, int* __restrict__ srcSorted, int n_edges, int n_nodes)
{
    const bool is64 = (flag[0] != 0);
    const int t  = blockIdx.x * blockDim.x + threadIdx.x;
    const int nt = gridDim.x * blockDim.x;
    for (int e = t; e < n_edges; e += nt) {
        const int src = load_idx(E, e, is64);
        const int dst = load_idx(E, n_edges + e, is64);
        if ((unsigned)src >= (unsigned)n_nodes || (unsigned)dst >= (unsigned)n_nodes) continue;
        const int p = atomicAdd(&pos[dst], 1);
        srcSorted[p] = src;
    }
}

// ---------------------------------------------------------------------------
// Gather-reduce (layer 1): H[node] = sum over edges(dst==node) of T[src].
// One 32-lane group per node, lane owns 4 contiguous floats. No atomics.
// ---------------------------------------------------------------------------
__global__ __launch_bounds__(256) void gather_vec(
    const float* __restrict__ T, const int* __restrict__ offs,
    const int* __restrict__ srcSorted, float* __restrict__ H, int n_nodes)
{
    const int l32  = threadIdx.x & 31;
    const int j0   = l32 * 4;
    const int grp  = (int)((blockIdx.x * blockDim.x + threadIdx.x) >> 5);
    const int ngrp = (int)((gridDim.x * blockDim.x) >> 5);
    for (int node = grp; node < n_nodes; node += ngrp) {
        const int k0 = offs[node];
        const int k1 = offs[node + 1];
        float4 acc = {0.f, 0.f, 0.f, 0.f};
        for (int k = k0; k < k1; ++k) {
            const int s = srcSorted[k];
            const float4 v = *(const float4*)(T + (size_t)s * HID + j0);
            acc.x += v.x; acc.y += v.y; acc.z += v.z; acc.w += v.w;
        }
        *(float4*)(H + (size_t)node * HID + j0) = acc;
    }
}

// ---------------------------------------------------------------------------
// Gather-reduce (readout): O[node] = bf + sum over edges(dst==node) of S[src].
// ---------------------------------------------------------------------------
__global__ __launch_bounds__(256) void gather_scalar(
    const float* __restrict__ S, const int* __restrict__ offs,
    const int* __restrict__ srcSorted, const float* __restrict__ bf,
    float* __restrict__ O, int n_nodes)
{
    const int t  = blockIdx.x * blockDim.x + threadIdx.x;
    const int nt = gridDim.x * blockDim.x;
    for (int node = t; node < n_nodes; node += nt) {
        const int k0 = offs[node];
        const int k1 = offs[node + 1];
        float acc = bf[0];
        for (int k = k0; k < k1; ++k) acc += S[srcSorted[k]];
        O[node] = acc;
    }
}

// ---------------------------------------------------------------------------
// Fallback atomic path (used only if workspace is too small for CSR)
// ---------------------------------------------------------------------------
__global__ __launch_bounds__(256) void scatter_vec(
    const float* __restrict__ T, const int* __restrict__ E,
    const int* __restrict__ flag, float* __restrict__ H,
    int n_edges, int n_nodes)
{
    const bool is64 = (flag[0] != 0);
    const int l32 = threadIdx.x & 31;
    const int j0  = l32 * 4;
    const int grp  = (int)((blockIdx.x * blockDim.x + threadIdx.x) >> 5);
    const int ngrp = (int)((gridDim.x * blockDim.x) >> 5);
    for (int e = grp; e < n_edges; e += ngrp) {
        const int src = load_idx(E, e, is64);
        const int dst = load_idx(E, n_edges + e, is64);
        if ((unsigned)src >= (unsigned)n_nodes || (unsigned)dst >= (unsigned)n_nodes) continue;
        const float4 v = *(const float4*)(T + (size_t)src * HID + j0);
        float* hp = H + (size_t)dst * HID + j0;
        unsafeAtomicAdd(hp + 0, v.x);
        unsafeAtomicAdd(hp + 1, v.y);
        unsafeAtomicAdd(hp + 2, v.z);
        unsafeAtomicAdd(hp + 3, v.w);
    }
}

__global__ __launch_bounds__(256) void scatter_scalar(
    const float* __restrict__ S, const int* __restrict__ E,
    const int* __restrict__ flag, float* __restrict__ O,
    int n_edges, int n_nodes)
{
    const bool is64 = (flag[0] != 0);
    const int t  = blockIdx.x * blockDim.x + threadIdx.x;
    const int nt = gridDim.x * blockDim.x;
    for (int e = t; e < n_edges; e += nt) {
        const int src = load_idx(E, e, is64);
        const int dst = load_idx(E, n_edges + e, is64);
        if ((unsigned)src >= (unsigned)n_nodes || (unsigned)dst >= (unsigned)n_nodes) continue;
        unsafeAtomicAdd(O + dst, S[src]);
    }
}

__global__ void init_out(float* __restrict__ O, const float* __restrict__ bf, int n) {
    int i = blockIdx.x * blockDim.x + threadIdx.x;
    if (i < n) O[i] = bf[0];
}

extern "C" void kernel_launch(void* const* d_in, const int* in_sizes, int n_in,
                              void* d_out, int out_size, void* d_ws, size_t ws_size,
                              hipStream_t stream) {
    const float* x  = (const float*)d_in[0];
    const int*   E  = (const int*)d_in[1];
    const float* W1 = (const float*)d_in[2];
    const float* b1 = (const float*)d_in[3];
    const float* W2 = (const float*)d_in[4];
    const float* b2 = (const float*)d_in[5];
    const float* Wf = (const float*)d_in[6];
    const float* bf = (const float*)d_in[7];
    float* out = (float*)d_out;

    const int n  = in_sizes[0] / HID;   // 50000 nodes
    const int ne = in_sizes[1] / 2;     // 800000 edges

    const size_t featB = (size_t)n * HID * 4;
    char* ws = (char*)d_ws;
    int*   flag = (int*)ws;
    float* t1   = (float*)(ws + 1024);
    float* h1   = (float*)(ws + 1024 + featB);
    char*  p    = ws + 1024 + 2 * featB;
    int*   cnt       = (int*)p;                 p += (size_t)n * 4;
    int*   offs      = (int*)p;                 p += (size_t)(n + 1) * 4;
    int*   pos       = (int*)p;                 p += (size_t)n * 4;
    int*   srcSorted = (int*)p;                 p += (size_t)ne * 4;
    const size_t needed = (size_t)(p - ws);
    float* s = t1;   // t1 dead after layer-1 aggregation; reuse for scalars

    detect_idx64<<<1, 64, 0, stream>>>(E, flag);

    // layer 1 per-node transform
    mlp_layer<<<512, 256, 0, stream>>>(x, W1, b1, nullptr, t1, nullptr, n, 0);

    if (ws_size >= needed) {
        // ---- CSR build (once per call; edge list is an input) ----
        (void)hipMemsetAsync(cnt, 0, (size_t)n * 4, stream);
        hist_dst<<<1024, 256, 0, stream>>>(E, flag, cnt, ne, n);
        scan_offsets<<<1, SCAN_THREADS, 0, stream>>>(cnt, offs, pos, n);
        build_perm<<<1024, 256, 0, stream>>>(E, flag, pos, srcSorted, ne, n);

        // ---- aggregation without atomics ----
        gather_vec<<<2048, 256, 0, stream>>>(t1, offs, srcSorted, h1, n);

        // layer 2 fused with readout: s[m] = relu(h1[m]@W2+b2) . Wf
        mlp_layer<<<512, 256, 0, stream>>>(h1, W2, b2, Wf, nullptr, s, n, 1);

        gather_scalar<<<512, 256, 0, stream>>>(s, offs, srcSorted, bf, out, n);
    } else {
        // ---- fallback: atomic scatter path ----
        (void)hipMemsetAsync(h1, 0, featB, stream);
        scatter_vec<<<8192, 256, 0, stream>>>(t1, E, flag, h1, ne, n);
        mlp_layer<<<512, 256, 0, stream>>>(h1, W2, b2, Wf, nullptr, s, n, 1);
        init_out<<<(n + 255) / 256, 256, 0, stream>>>(out, bf, n);
        scatter_scalar<<<2048, 256, 0, stream>>>(s, E, flag, out, ne, n);
    }
}

// Round 4
// 345.228 us; speedup vs baseline: 4.8361x; 1.5768x over previous
//
#include <hip/hip_runtime.h>

#define HID 128
#define BM 128
#define BK 32
#define SCAN_THREADS 1024

// ---------------------------------------------------------------------------
// Detect whether edge_index was materialized as int64 (odd 32-bit words all 0)
// or int32. Values are node ids in [0, 50000) so the high word of int64 is 0.
// ---------------------------------------------------------------------------
__global__ void detect_idx64(const int* __restrict__ E, int* __restrict__ flag) {
    int l = threadIdx.x;                       // 64 threads
    int v = E[2 * l + 1] | E[2 * (l + 64) + 1];
    unsigned long long b = __ballot(v != 0);
    if (l == 0) flag[0] = (b == 0ull) ? 1 : 0;
}

__device__ __forceinline__ int load_idx(const int* __restrict__ E, int pos, bool is64) {
    return is64 ? E[2 * pos] : E[pos];
}

// ---------------------------------------------------------------------------
// Register-blocked SGEMM: T = relu(X @ W + B)  (X: n x 128, W: 128 x 128)
// Block: 256 threads (16x16), tile BM=128 rows x 128 cols, BK=32 k-slice.
// Each thread: 8x8 micro-tile in registers -> 64 FMA per 4 ds_read_b128.
// mode 0: write full T rows.  mode 1: fuse dot with Wf, write scalar S only.
// ---------------------------------------------------------------------------
__global__ __launch_bounds__(256, 2) void mlp_gemm(
    const float* __restrict__ X, const float* __restrict__ W,
    const float* __restrict__ Bv, const float* __restrict__ Wf,
    float* __restrict__ T, float* __restrict__ S, int n, int mode)
{
    __shared__ float Xs[BK][BM + 1];     // transposed X tile, +1 pad
    __shared__ float Wsh[BK][HID];       // W k-slice, natural layout

    const int t  = threadIdx.x;
    const int tn = t & 15;               // column-group 0..15 (8 cols each)
    const int tm = t >> 4;               // row-group 0..15 (8 rows each)
    const int base = blockIdx.x * BM;

    float acc[8][8];
#pragma unroll
    for (int r = 0; r < 8; ++r)
#pragma unroll
        for (int c = 0; c < 8; ++c) acc[r][c] = 0.f;

    for (int kb = 0; kb < HID; kb += BK) {
        // stage X tile (transposed): rows base..base+127, k-cols kb..kb+31
#pragma unroll
        for (int pass = 0; pass < 4; ++pass) {
            const int row = pass * 32 + (t >> 3);
            const int kc  = (t & 7) * 4;
            float4 v = {0.f, 0.f, 0.f, 0.f};
            const int gr = base + row;
            if (gr < n) v = *(const float4*)(X + (size_t)gr * HID + kb + kc);
            Xs[kc + 0][row] = v.x;
            Xs[kc + 1][row] = v.y;
            Xs[kc + 2][row] = v.z;
            Xs[kc + 3][row] = v.w;
        }
        // stage W k-slice: rows kb..kb+31 (full 128 cols)
#pragma unroll
        for (int pass = 0; pass < 4; ++pass) {
            const int kr = pass * 8 + (t >> 5);
            const int nc = (t & 31) * 4;
            *(float4*)(&Wsh[kr][nc]) =
                *(const float4*)(W + (size_t)(kb + kr) * HID + nc);
        }
        __syncthreads();

#pragma unroll
        for (int k = 0; k < BK; ++k) {
            float xr[8], wc[8];
            *(float4*)&xr[0] = *(const float4*)&Xs[k][tm * 8];
            *(float4*)&xr[4] = *(const float4*)&Xs[k][tm * 8 + 4];
            *(float4*)&wc[0] = *(const float4*)&Wsh[k][tn * 8];
            *(float4*)&wc[4] = *(const float4*)&Wsh[k][tn * 8 + 4];
#pragma unroll
            for (int r = 0; r < 8; ++r)
#pragma unroll
                for (int c = 0; c < 8; ++c)
                    acc[r][c] = fmaf(xr[r], wc[c], acc[r][c]);
        }
        __syncthreads();
    }

    // epilogue: bias + relu
    float bv[8];
    *(float4*)&bv[0] = *(const float4*)(Bv + tn * 8);
    *(float4*)&bv[4] = *(const float4*)(Bv + tn * 8 + 4);

    if (mode == 0) {
#pragma unroll
        for (int r = 0; r < 8; ++r) {
            const int gr = base + tm * 8 + r;
            if (gr >= n) break;
            float o[8];
#pragma unroll
            for (int c = 0; c < 8; ++c) o[c] = fmaxf(acc[r][c] + bv[c], 0.f);
            *(float4*)(T + (size_t)gr * HID + tn * 8)     = *(float4*)&o[0];
            *(float4*)(T + (size_t)gr * HID + tn * 8 + 4) = *(float4*)&o[4];
        }
    } else {
        float wf[8];
        *(float4*)&wf[0] = *(const float4*)(Wf + tn * 8);
        *(float4*)&wf[4] = *(const float4*)(Wf + tn * 8 + 4);
        float p[8];
#pragma unroll
        for (int r = 0; r < 8; ++r) {
            float s = 0.f;
#pragma unroll
            for (int c = 0; c < 8; ++c)
                s += fmaxf(acc[r][c] + bv[c], 0.f) * wf[c];
            p[r] = s;
        }
        // reduce across the 16 column-threads (lane bits 0..3)
#pragma unroll
        for (int m = 1; m <= 8; m <<= 1)
#pragma unroll
            for (int r = 0; r < 8; ++r) p[r] += __shfl_xor(p[r], m);
        if (tn == 0) {
#pragma unroll
            for (int r = 0; r < 8; ++r) {
                const int gr = base + tm * 8 + r;
                if (gr < n) S[gr] = p[r];
            }
        }
    }
}

// ---------------------------------------------------------------------------
// CSR build: histogram of dst, block scan, permute src ids into dst order.
// ---------------------------------------------------------------------------
__global__ __launch_bounds__(256) void hist_dst(
    const int* __restrict__ E, const int* __restrict__ flag,
    int* __restrict__ cnt, int n_edges, int n_nodes)
{
    const bool is64 = (flag[0] != 0);
    const int t  = blockIdx.x * blockDim.x + threadIdx.x;
    const int nt = gridDim.x * blockDim.x;
    for (int e = t; e < n_edges; e += nt) {
        const int dst = load_idx(E, n_edges + e, is64);
        if ((unsigned)dst < (unsigned)n_nodes) atomicAdd(&cnt[dst], 1);
    }
}

__global__ __launch_bounds__(SCAN_THREADS) void scan_offsets(
    const int* __restrict__ cnt, int* __restrict__ offs, int* __restrict__ pos, int n)
{
    __shared__ int sums[SCAN_THREADS];
    const int t = threadIdx.x;
    const int chunk = (n + SCAN_THREADS - 1) / SCAN_THREADS;
    const int lo = t * chunk;
    const int hi = min(lo + chunk, n);
    int s = 0;
    for (int i = lo; i < hi; ++i) s += cnt[i];
    sums[t] = s;
    __syncthreads();
    for (int d = 1; d < SCAN_THREADS; d <<= 1) {
        int v = (t >= d) ? sums[t - d] : 0;
        __syncthreads();
        sums[t] += v;
        __syncthreads();
    }
    int run = (t > 0) ? sums[t - 1] : 0;   // exclusive prefix of this chunk
    for (int i = lo; i < hi; ++i) {
        offs[i] = run;
        pos[i]  = run;
        run += cnt[i];
    }
    if (t == SCAN_THREADS - 1) offs[n] = run;
}

__global__ __launch_bounds__(256) void build_perm(
    const int* __restrict__ E, const int* __restrict__ flag,
    int* __restrict__ pos, int* __restrict__ srcSorted, int n_edges, int n_nodes)
{
    const bool is64 = (flag[0] != 0);
    const int t  = blockIdx.x * blockDim.x + threadIdx.x;
    const int nt = gridDim.x * blockDim.x;
    for (int e = t; e < n_edges; e += nt) {
        const int src = load_idx(E, e, is64);
        const int dst = load_idx(E, n_edges + e, is64);
        if ((unsigned)src >= (unsigned)n_nodes || (unsigned)dst >= (unsigned)n_nodes) continue;
        const int p = atomicAdd(&pos[dst], 1);
        srcSorted[p] = src;
    }
}

// ---------------------------------------------------------------------------
// Gather-reduce (layer 1): H[node] = sum over edges(dst==node) of T[src].
// One 32-lane group per node, lane owns 4 contiguous floats. No atomics.
// ---------------------------------------------------------------------------
__global__ __launch_bounds__(256) void gather_vec(
    const float* __restrict__ T, const int* __restrict__ offs,
    const int* __restrict__ srcSorted, float* __restrict__ H, int n_nodes)
{
    const int l32  = threadIdx.x & 31;
    const int j0   = l32 * 4;
    const int grp  = (int)((blockIdx.x * blockDim.x + threadIdx.x) >> 5);
    const int ngrp = (int)((gridDim.x * blockDim.x) >> 5);
    for (int node = grp; node < n_nodes; node += ngrp) {
        const int k0 = offs[node];
        const int k1 = offs[node + 1];
        float4 acc = {0.f, 0.f, 0.f, 0.f};
        for (int k = k0; k < k1; ++k) {
            const int s = srcSorted[k];
            const float4 v = *(const float4*)(T + (size_t)s * HID + j0);
            acc.x += v.x; acc.y += v.y; acc.z += v.z; acc.w += v.w;
        }
        *(float4*)(H + (size_t)node * HID + j0) = acc;
    }
}

// ---------------------------------------------------------------------------
// Gather-reduce (readout): O[node] = bf + sum over edges(dst==node) of S[src].
// ---------------------------------------------------------------------------
__global__ __launch_bounds__(256) void gather_scalar(
    const float* __restrict__ S, const int* __restrict__ offs,
    const int* __restrict__ srcSorted, const float* __restrict__ bf,
    float* __restrict__ O, int n_nodes)
{
    const int t  = blockIdx.x * blockDim.x + threadIdx.x;
    const int nt = gridDim.x * blockDim.x;
    for (int node = t; node < n_nodes; node += nt) {
        const int k0 = offs[node];
        const int k1 = offs[node + 1];
        float acc = bf[0];
        for (int k = k0; k < k1; ++k) acc += S[srcSorted[k]];
        O[node] = acc;
    }
}

// ---------------------------------------------------------------------------
// Fallback atomic path (used only if workspace is too small for CSR)
// ---------------------------------------------------------------------------
__global__ __launch_bounds__(256) void scatter_vec(
    const float* __restrict__ T, const int* __restrict__ E,
    const int* __restrict__ flag, float* __restrict__ H,
    int n_edges, int n_nodes)
{
    const bool is64 = (flag[0] != 0);
    const int l32 = threadIdx.x & 31;
    const int j0  = l32 * 4;
    const int grp  = (int)((blockIdx.x * blockDim.x + threadIdx.x) >> 5);
    const int ngrp = (int)((gridDim.x * blockDim.x) >> 5);
    for (int e = grp; e < n_edges; e += ngrp) {
        const int src = load_idx(E, e, is64);
        const int dst = load_idx(E, n_edges + e, is64);
        if ((unsigned)src >= (unsigned)n_nodes || (unsigned)dst >= (unsigned)n_nodes) continue;
        const float4 v = *(const float4*)(T + (size_t)src * HID + j0);
        float* hp = H + (size_t)dst * HID + j0;
        unsafeAtomicAdd(hp + 0, v.x);
        unsafeAtomicAdd(hp + 1, v.y);
        unsafeAtomicAdd(hp + 2, v.z);
        unsafeAtomicAdd(hp + 3, v.w);
    }
}

__global__ __launch_bounds__(256) void scatter_scalar(
    const float* __restrict__ S, const int* __restrict__ E,
    const int* __restrict__ flag, float* __restrict__ O,
    int n_edges, int n_nodes)
{
    const bool is64 = (flag[0] != 0);
    const int t  = blockIdx.x * blockDim.x + threadIdx.x;
    const int nt = gridDim.x * blockDim.x;
    for (int e = t; e < n_edges; e += nt) {
        const int src = load_idx(E, e, is64);
        const int dst = load_idx(E, n_edges + e, is64);
        if ((unsigned)src >= (unsigned)n_nodes || (unsigned)dst >= (unsigned)n_nodes) continue;
        unsafeAtomicAdd(O + dst, S[src]);
    }
}

__global__ void init_out(float* __restrict__ O, const float* __restrict__ bf, int n) {
    int i = blockIdx.x * blockDim.x + threadIdx.x;
    if (i < n) O[i] = bf[0];
}

extern "C" void kernel_launch(void* const* d_in, const int* in_sizes, int n_in,
                              void* d_out, int out_size, void* d_ws, size_t ws_size,
                              hipStream_t stream) {
    const float* x  = (const float*)d_in[0];
    const int*   E  = (const int*)d_in[1];
    const float* W1 = (const float*)d_in[2];
    const float* b1 = (const float*)d_in[3];
    const float* W2 = (const float*)d_in[4];
    const float* b2 = (const float*)d_in[5];
    const float* Wf = (const float*)d_in[6];
    const float* bf = (const float*)d_in[7];
    float* out = (float*)d_out;

    const int n  = in_sizes[0] / HID;   // 50000 nodes
    const int ne = in_sizes[1] / 2;     // 800000 edges

    const size_t featB = (size_t)n * HID * 4;
    char* ws = (char*)d_ws;
    int*   flag = (int*)ws;
    float* t1   = (float*)(ws + 1024);
    float* h1   = (float*)(ws + 1024 + featB);
    char*  p    = ws + 1024 + 2 * featB;
    int*   cnt       = (int*)p;                 p += (size_t)n * 4;
    int*   offs      = (int*)p;                 p += (size_t)(n + 1) * 4;
    int*   pos       = (int*)p;                 p += (size_t)n * 4;
    int*   srcSorted = (int*)p;                 p += (size_t)ne * 4;
    const size_t needed = (size_t)(p - ws);
    float* s = t1;   // t1 dead after layer-1 aggregation; reuse for scalars

    const int gemm_grid = (n + BM - 1) / BM;

    detect_idx64<<<1, 64, 0, stream>>>(E, flag);

    // layer 1 per-node transform
    mlp_gemm<<<gemm_grid, 256, 0, stream>>>(x, W1, b1, nullptr, t1, nullptr, n, 0);

    if (ws_size >= needed) {
        // ---- CSR build (once per call; edge list is an input) ----
        (void)hipMemsetAsync(cnt, 0, (size_t)n * 4, stream);
        hist_dst<<<1024, 256, 0, stream>>>(E, flag, cnt, ne, n);
        scan_offsets<<<1, SCAN_THREADS, 0, stream>>>(cnt, offs, pos, n);
        build_perm<<<1024, 256, 0, stream>>>(E, flag, pos, srcSorted, ne, n);

        // ---- aggregation without atomics ----
        gather_vec<<<2048, 256, 0, stream>>>(t1, offs, srcSorted, h1, n);

        // layer 2 fused with readout: s[m] = relu(h1[m]@W2+b2) . Wf
        mlp_gemm<<<gemm_grid, 256, 0, stream>>>(h1, W2, b2, Wf, nullptr, s, n, 1);

        gather_scalar<<<512, 256, 0, stream>>>(s, offs, srcSorted, bf, out, n);
    } else {
        // ---- fallback: atomic scatter path ----
        (void)hipMemsetAsync(h1, 0, featB, stream);
        scatter_vec<<<8192, 256, 0, stream>>>(t1, E, flag, h1, ne, n);
        mlp_gemm<<<gemm_grid, 256, 0, stream>>>(h1, W2, b2, Wf, nullptr, s, n, 1);
        init_out<<<(n + 255) / 256, 256, 0, stream>>>(out, bf, n);
        scatter_scalar<<<2048, 256, 0, stream>>>(s, E, flag, out, ne, n);
    }
}

// Round 5
// 241.584 us; speedup vs baseline: 6.9109x; 1.4290x over previous
//
#include <hip/hip_runtime.h>

#define HID 128
#define BM 128
#define BK 32

typedef unsigned short ushort_t;
typedef unsigned int uint_t;

__device__ __forceinline__ float bflo(uint_t u) { return __uint_as_float(u << 16); }
__device__ __forceinline__ float bfhi(uint_t u) { return __uint_as_float(u & 0xFFFF0000u); }
__device__ __forceinline__ uint_t f2bf(float f) {
    uint_t x = __float_as_uint(f);
    return (x + 0x7FFFu + ((x >> 16) & 1u)) >> 16;   // RNE
}

// ---------------------------------------------------------------------------
// Detect whether edge_index was materialized as int64 (odd 32-bit words all 0)
// or int32. Values are node ids in [0, 50000) so the high word of int64 is 0.
// ---------------------------------------------------------------------------
__global__ void detect_idx64(const int* __restrict__ E, int* __restrict__ flag) {
    int l = threadIdx.x;                       // 64 threads
    int v = E[2 * l + 1] | E[2 * (l + 64) + 1];
    unsigned long long b = __ballot(v != 0);
    if (l == 0) flag[0] = (b == 0ull) ? 1 : 0;
}

__device__ __forceinline__ int load_idx(const int* __restrict__ E, int pos, bool is64) {
    return is64 ? E[2 * pos] : E[pos];
}

// ---------------------------------------------------------------------------
// Register-blocked SGEMM: T = relu(X @ W + B)  (X: n x 128, W: 128 x 128)
// Block: 256 threads (16x16), tile BM=128 rows, BK=32 k-slice, 8x8 micro-tile.
// mode 0: write full T rows as bf16.  mode 1: fuse dot with Wf, write S only.
// ---------------------------------------------------------------------------
__global__ __launch_bounds__(256, 2) void mlp_gemm(
    const float* __restrict__ X, const float* __restrict__ W,
    const float* __restrict__ Bv, const float* __restrict__ Wf,
    ushort_t* __restrict__ T, float* __restrict__ S, int n, int mode)
{
    __shared__ float Xs[BK][BM + 1];     // transposed X tile, +1 pad
    __shared__ float Wsh[BK][HID];       // W k-slice, natural layout

    const int t  = threadIdx.x;
    const int tn = t & 15;               // column-group 0..15 (8 cols each)
    const int tm = t >> 4;               // row-group 0..15 (8 rows each)
    const int base = blockIdx.x * BM;

    float acc[8][8];
#pragma unroll
    for (int r = 0; r < 8; ++r)
#pragma unroll
        for (int c = 0; c < 8; ++c) acc[r][c] = 0.f;

    for (int kb = 0; kb < HID; kb += BK) {
#pragma unroll
        for (int pass = 0; pass < 4; ++pass) {
            const int row = pass * 32 + (t >> 3);
            const int kc  = (t & 7) * 4;
            float4 v = {0.f, 0.f, 0.f, 0.f};
            const int gr = base + row;
            if (gr < n) v = *(const float4*)(X + (size_t)gr * HID + kb + kc);
            Xs[kc + 0][row] = v.x;
            Xs[kc + 1][row] = v.y;
            Xs[kc + 2][row] = v.z;
            Xs[kc + 3][row] = v.w;
        }
#pragma unroll
        for (int pass = 0; pass < 4; ++pass) {
            const int kr = pass * 8 + (t >> 5);
            const int nc = (t & 31) * 4;
            *(float4*)(&Wsh[kr][nc]) =
                *(const float4*)(W + (size_t)(kb + kr) * HID + nc);
        }
        __syncthreads();

#pragma unroll
        for (int k = 0; k < BK; ++k) {
            float xr[8], wc[8];
            *(float4*)&xr[0] = *(const float4*)&Xs[k][tm * 8];
            *(float4*)&xr[4] = *(const float4*)&Xs[k][tm * 8 + 4];
            *(float4*)&wc[0] = *(const float4*)&Wsh[k][tn * 8];
            *(float4*)&wc[4] = *(const float4*)&Wsh[k][tn * 8 + 4];
#pragma unroll
            for (int r = 0; r < 8; ++r)
#pragma unroll
                for (int c = 0; c < 8; ++c)
                    acc[r][c] = fmaf(xr[r], wc[c], acc[r][c]);
        }
        __syncthreads();
    }

    float bv[8];
    *(float4*)&bv[0] = *(const float4*)(Bv + tn * 8);
    *(float4*)&bv[4] = *(const float4*)(Bv + tn * 8 + 4);

    if (mode == 0) {
#pragma unroll
        for (int r = 0; r < 8; ++r) {
            const int gr = base + tm * 8 + r;
            if (gr >= n) break;
            uint_t w[4];
#pragma unroll
            for (int c = 0; c < 4; ++c) {
                const float lo = fmaxf(acc[r][2 * c]     + bv[2 * c],     0.f);
                const float hi = fmaxf(acc[r][2 * c + 1] + bv[2 * c + 1], 0.f);
                w[c] = f2bf(lo) | (f2bf(hi) << 16);
            }
            *(uint4*)(T + (size_t)gr * HID + tn * 8) = *(uint4*)&w[0];
        }
    } else {
        float wf[8];
        *(float4*)&wf[0] = *(const float4*)(Wf + tn * 8);
        *(float4*)&wf[4] = *(const float4*)(Wf + tn * 8 + 4);
        float p[8];
#pragma unroll
        for (int r = 0; r < 8; ++r) {
            float s = 0.f;
#pragma unroll
            for (int c = 0; c < 8; ++c)
                s += fmaxf(acc[r][c] + bv[c], 0.f) * wf[c];
            p[r] = s;
        }
#pragma unroll
        for (int m = 1; m <= 8; m <<= 1)
#pragma unroll
            for (int r = 0; r < 8; ++r) p[r] += __shfl_xor(p[r], m);
        if (tn == 0) {
#pragma unroll
            for (int r = 0; r < 8; ++r) {
                const int gr = base + tm * 8 + r;
                if (gr < n) S[gr] = p[r];
            }
        }
    }
}

// ---------------------------------------------------------------------------
// CSR build: histogram of dst, hierarchical scan, permute src into dst order.
// ---------------------------------------------------------------------------
__global__ __launch_bounds__(256) void hist_dst(
    const int* __restrict__ E, const int* __restrict__ flag,
    int* __restrict__ cnt, int n_edges, int n_nodes)
{
    const bool is64 = (flag[0] != 0);
    const int t  = blockIdx.x * blockDim.x + threadIdx.x;
    const int nt = gridDim.x * blockDim.x;
    for (int e = t; e < n_edges; e += nt) {
        const int dst = load_idx(E, n_edges + e, is64);
        if ((unsigned)dst < (unsigned)n_nodes) atomicAdd(&cnt[dst], 1);
    }
}

// per-256-chunk exclusive scan; block sum out
__global__ __launch_bounds__(256) void scan_blk(
    const int* __restrict__ cnt, int* __restrict__ offs,
    int* __restrict__ blockSum, int n)
{
    __shared__ int sd[256];
    const int t = threadIdx.x;
    const int i = blockIdx.x * 256 + t;
    const int v = (i < n) ? cnt[i] : 0;
    sd[t] = v;
    __syncthreads();
    for (int d = 1; d < 256; d <<= 1) {
        const int u = (t >= d) ? sd[t - d] : 0;
        __syncthreads();
        sd[t] += u;
        __syncthreads();
    }
    if (i < n) offs[i] = sd[t] - v;          // local exclusive
    if (t == 255) blockSum[blockIdx.x] = sd[255];
}

// scan the (<=256*chunk) block sums in one small block; writes offs[n]=total
__global__ __launch_bounds__(256) void scan_top(
    int* __restrict__ blockSum, int* __restrict__ offs, int nb, int n)
{
    __shared__ int sd[256];
    const int t = threadIdx.x;
    const int chunk = (nb + 255) / 256;
    const int lo = t * chunk;
    const int hi = min(lo + chunk, nb);
    int s = 0;
    for (int i = lo; i < hi; ++i) s += blockSum[i];
    sd[t] = s;
    __syncthreads();
    for (int d = 1; d < 256; d <<= 1) {
        const int u = (t >= d) ? sd[t - d] : 0;
        __syncthreads();
        sd[t] += u;
        __syncthreads();
    }
    int run = sd[t] - s;                      // exclusive base of this chunk
    for (int i = lo; i < hi; ++i) {
        const int c = blockSum[i];
        blockSum[i] = run;                    // becomes block base
        run += c;
    }
    if (t == 255) offs[n] = sd[255];
}

__global__ __launch_bounds__(256) void scan_add(
    int* __restrict__ offs, int* __restrict__ pos,
    const int* __restrict__ blockSum, int n)
{
    const int i = blockIdx.x * 256 + threadIdx.x;
    if (i < n) {
        const int o = offs[i] + blockSum[blockIdx.x];
        offs[i] = o;
        pos[i]  = o;
    }
}

__global__ __launch_bounds__(256) void build_perm(
    const int* __restrict__ E, const int* __restrict__ flag,
    int* __restrict__ pos, int* __restrict__ srcSorted, int n_edges, int n_nodes)
{
    const bool is64 = (flag[0] != 0);
    const int t  = blockIdx.x * blockDim.x + threadIdx.x;
    const int nt = gridDim.x * blockDim.x;
    for (int e = t; e < n_edges; e += nt) {
        const int src = load_idx(E, e, is64);
        const int dst = load_idx(E, n_edges + e, is64);
        if ((unsigned)src >= (unsigned)n_nodes || (unsigned)dst >= (unsigned)n_nodes) continue;
        const int p = atomicAdd(&pos[dst], 1);
        srcSorted[p] = src;
    }
}

// ---------------------------------------------------------------------------
// Gather-reduce (layer 1): H[node] = sum over edges(dst==node) of T[src].
// One 32-lane group per node, lane owns 4 features (bf16 in T, fp32 acc).
// ---------------------------------------------------------------------------
__global__ __launch_bounds__(256) void gather_vec(
    const ushort_t* __restrict__ T, const int* __restrict__ offs,
    const int* __restrict__ srcSorted, float* __restrict__ H, int n_nodes)
{
    const int l32  = threadIdx.x & 31;
    const int j0   = l32 * 4;
    const int grp  = (int)((blockIdx.x * blockDim.x + threadIdx.x) >> 5);
    const int ngrp = (int)((gridDim.x * blockDim.x) >> 5);
    for (int node = grp; node < n_nodes; node += ngrp) {
        const int k0 = offs[node];
        const int k1 = offs[node + 1];
        float4 acc = {0.f, 0.f, 0.f, 0.f};
        for (int k = k0; k < k1; ++k) {
            const int s = srcSorted[k];
            const uint2 u = *(const uint2*)(T + (size_t)s * HID + j0);
            acc.x += bflo(u.x); acc.y += bfhi(u.x);
            acc.z += bflo(u.y); acc.w += bfhi(u.y);
        }
        *(float4*)(H + (size_t)node * HID + j0) = acc;
    }
}

// ---------------------------------------------------------------------------
// Gather-reduce (readout): O[node] = bf + sum over edges(dst==node) of S[src].
// ---------------------------------------------------------------------------
__global__ __launch_bounds__(256) void gather_scalar(
    const float* __restrict__ S, const int* __restrict__ offs,
    const int* __restrict__ srcSorted, const float* __restrict__ bf,
    float* __restrict__ O, int n_nodes)
{
    const int t  = blockIdx.x * blockDim.x + threadIdx.x;
    const int nt = gridDim.x * blockDim.x;
    for (int node = t; node < n_nodes; node += nt) {
        const int k0 = offs[node];
        const int k1 = offs[node + 1];
        float acc = bf[0];
        for (int k = k0; k < k1; ++k) acc += S[srcSorted[k]];
        O[node] = acc;
    }
}

// ---------------------------------------------------------------------------
// Fallback atomic path (used only if workspace is too small for CSR)
// ---------------------------------------------------------------------------
__global__ __launch_bounds__(256) void scatter_vec(
    const ushort_t* __restrict__ T, const int* __restrict__ E,
    const int* __restrict__ flag, float* __restrict__ H,
    int n_edges, int n_nodes)
{
    const bool is64 = (flag[0] != 0);
    const int l32 = threadIdx.x & 31;
    const int j0  = l32 * 4;
    const int grp  = (int)((blockIdx.x * blockDim.x + threadIdx.x) >> 5);
    const int ngrp = (int)((gridDim.x * blockDim.x) >> 5);
    for (int e = grp; e < n_edges; e += ngrp) {
        const int src = load_idx(E, e, is64);
        const int dst = load_idx(E, n_edges + e, is64);
        if ((unsigned)src >= (unsigned)n_nodes || (unsigned)dst >= (unsigned)n_nodes) continue;
        const uint2 u = *(const uint2*)(T + (size_t)src * HID + j0);
        float* hp = H + (size_t)dst * HID + j0;
        unsafeAtomicAdd(hp + 0, bflo(u.x));
        unsafeAtomicAdd(hp + 1, bfhi(u.x));
        unsafeAtomicAdd(hp + 2, bflo(u.y));
        unsafeAtomicAdd(hp + 3, bfhi(u.y));
    }
}

__global__ __launch_bounds__(256) void scatter_scalar(
    const float* __restrict__ S, const int* __restrict__ E,
    const int* __restrict__ flag, float* __restrict__ O,
    int n_edges, int n_nodes)
{
    const bool is64 = (flag[0] != 0);
    const int t  = blockIdx.x * blockDim.x + threadIdx.x;
    const int nt = gridDim.x * blockDim.x;
    for (int e = t; e < n_edges; e += nt) {
        const int src = load_idx(E, e, is64);
        const int dst = load_idx(E, n_edges + e, is64);
        if ((unsigned)src >= (unsigned)n_nodes || (unsigned)dst >= (unsigned)n_nodes) continue;
        unsafeAtomicAdd(O + dst, S[src]);
    }
}

__global__ void init_out(float* __restrict__ O, const float* __restrict__ bf, int n) {
    int i = blockIdx.x * blockDim.x + threadIdx.x;
    if (i < n) O[i] = bf[0];
}

extern "C" void kernel_launch(void* const* d_in, const int* in_sizes, int n_in,
                              void* d_out, int out_size, void* d_ws, size_t ws_size,
                              hipStream_t stream) {
    const float* x  = (const float*)d_in[0];
    const int*   E  = (const int*)d_in[1];
    const float* W1 = (const float*)d_in[2];
    const float* b1 = (const float*)d_in[3];
    const float* W2 = (const float*)d_in[4];
    const float* b2 = (const float*)d_in[5];
    const float* Wf = (const float*)d_in[6];
    const float* bf = (const float*)d_in[7];
    float* out = (float*)d_out;

    const int n  = in_sizes[0] / HID;   // 50000 nodes
    const int ne = in_sizes[1] / 2;     // 800000 edges
    const int nb = (n + 255) / 256;     // scan blocks

    const size_t featB = (size_t)n * HID * 4;
    char* ws = (char*)d_ws;
    int*   flag = (int*)ws;
    ushort_t* t1 = (ushort_t*)(ws + 1024);             // n*128 bf16 (within featB slot)
    float* h1   = (float*)(ws + 1024 + featB);
    char*  p    = ws + 1024 + 2 * featB;
    int*   cnt       = (int*)p;                 p += (size_t)n * 4;
    int*   offs      = (int*)p;                 p += (size_t)(n + 1) * 4;
    int*   pos       = (int*)p;                 p += (size_t)n * 4;
    int*   srcSorted = (int*)p;                 p += (size_t)ne * 4;
    int*   blockSum  = (int*)p;                 p += (size_t)nb * 4;
    const size_t needed = (size_t)(p - ws);
    float* s = (float*)(ws + 1024);   // t1 dead after aggregation; reuse slot

    const int gemm_grid = (n + BM - 1) / BM;

    detect_idx64<<<1, 64, 0, stream>>>(E, flag);

    // layer 1 per-node transform (bf16 out)
    mlp_gemm<<<gemm_grid, 256, 0, stream>>>(x, W1, b1, nullptr, t1, nullptr, n, 0);

    if (ws_size >= needed) {
        // ---- CSR build ----
        (void)hipMemsetAsync(cnt, 0, (size_t)n * 4, stream);
        hist_dst<<<1024, 256, 0, stream>>>(E, flag, cnt, ne, n);
        scan_blk<<<nb, 256, 0, stream>>>(cnt, offs, blockSum, n);
        scan_top<<<1, 256, 0, stream>>>(blockSum, offs, nb, n);
        scan_add<<<nb, 256, 0, stream>>>(offs, pos, blockSum, n);
        build_perm<<<1024, 256, 0, stream>>>(E, flag, pos, srcSorted, ne, n);

        // ---- aggregation without atomics ----
        gather_vec<<<2048, 256, 0, stream>>>(t1, offs, srcSorted, h1, n);

        // layer 2 fused with readout: s[m] = relu(h1[m]@W2+b2) . Wf
        mlp_gemm<<<gemm_grid, 256, 0, stream>>>(h1, W2, b2, Wf, nullptr, s, n, 1);

        gather_scalar<<<512, 256, 0, stream>>>(s, offs, srcSorted, bf, out, n);
    } else {
        // ---- fallback: atomic scatter path ----
        (void)hipMemsetAsync(h1, 0, featB, stream);
        scatter_vec<<<8192, 256, 0, stream>>>(t1, E, flag, h1, ne, n);
        mlp_gemm<<<gemm_grid, 256, 0, stream>>>(h1, W2, b2, Wf, nullptr, s, n, 1);
        init_out<<<(n + 255) / 256, 256, 0, stream>>>(out, bf, n);
        scatter_scalar<<<2048, 256, 0, stream>>>(s, E, flag, out, ne, n);
    }
}